// Round 10
// baseline (251.349 us; speedup 1.0000x reference)
//
#include <hip/hip_runtime.h>
#include <hip/hip_bf16.h>
#include <hip/hip_fp16.h>
#include <math.h>

typedef _Float16 f16x8 __attribute__((ext_vector_type(8)));
typedef __fp16  h16x2 __attribute__((ext_vector_type(2)));
typedef float f32x4 __attribute__((ext_vector_type(4)));

#define S_LEN 1024
#define DH 64
#define KVB 64
#define NIT 16
#define KROW 72   // padded LDS row (elements)
#define THR 11.0f // defer-max threshold (log2 domain): P <= 2^11, fp16-safe

__device__ __forceinline__ unsigned rotl(unsigned x, unsigned r) {
  return __builtin_amdgcn_alignbit(x, x, 32u - r);  // single v_alignbit_b32
}

// JAX threefry2x32, key=(0,42), counts=(0,e) [threefry_partitionable].
// draw = x0 ^ x1; keep = top bit == 0 (uniform < 0.5).
__device__ __forceinline__ bool keep_bit(unsigned e) {
  const unsigned ks1 = 42u;
  const unsigned ks2 = 0x1BD11BF0u;  // 0 ^ 42 ^ 0x1BD11BDA
  unsigned x0 = 0u;
  unsigned x1 = e + ks1;
#define TFR(Ra,Rb,Rc,Rd) \
  x0 += x1; x1 = rotl(x1, Ra); x1 ^= x0; \
  x0 += x1; x1 = rotl(x1, Rb); x1 ^= x0; \
  x0 += x1; x1 = rotl(x1, Rc); x1 ^= x0; \
  x0 += x1; x1 = rotl(x1, Rd); x1 ^= x0;
  TFR(13u,15u,26u, 6u)  x0 += ks1; x1 += ks2 + 1u;
  TFR(17u,29u,16u,24u)  x0 += ks2; x1 += 2u;
  TFR(13u,15u,26u, 6u)  /* +0 */   x1 += ks1 + 3u;
  TFR(17u,29u,16u,24u)  x0 += ks1; x1 += ks2 + 4u;
  TFR(13u,15u,26u, 6u)  x0 += ks2; x1 += 5u;
#undef TFR
  return ((x0 ^ x1) >> 31) == 0u;
}

__device__ __forceinline__ f16x8 pk8(f32x4 a, f32x4 b) {
  h16x2 p0 = __builtin_amdgcn_cvt_pkrtz(a[0], a[1]);
  h16x2 p1 = __builtin_amdgcn_cvt_pkrtz(a[2], a[3]);
  h16x2 p2 = __builtin_amdgcn_cvt_pkrtz(b[0], b[1]);
  h16x2 p3 = __builtin_amdgcn_cvt_pkrtz(b[2], b[3]);
  f16x8 r;
  r[0]=(_Float16)p0[0]; r[1]=(_Float16)p0[1]; r[2]=(_Float16)p1[0]; r[3]=(_Float16)p1[1];
  r[4]=(_Float16)p2[0]; r[5]=(_Float16)p2[1]; r[6]=(_Float16)p3[0]; r[7]=(_Float16)p3[1];
  return r;
}

__global__ __launch_bounds__(256)
void attn_dropout_kernel(const float* __restrict__ Q, const float* __restrict__ K,
                         const float* __restrict__ V, float* __restrict__ out) {
  // One block = one (b,h) x 64 q-rows; 4 waves x 16 q-rows, all 64 k-cols.
  // K: LDS-staged (reg-prefetched). V: LDS ELIMINATED — B-fragments loaded
  // directly from global (coalesced 4x64B per inst, L2-resident, reused 64x).
  __shared__ _Float16 Kl[KVB][KROW];      // [k][d]
  __shared__ _Float16 Pl[4][16][KROW];    // per-wave P tile

  const unsigned bh   = blockIdx.x >> 4;
  const unsigned q0   = (blockIdx.x & 15u) * 64u;
  const unsigned tid  = threadIdx.x;
  const unsigned w    = tid >> 6;
  const unsigned lane = tid & 63u;
  const unsigned g    = lane >> 4;     // 0..3
  const unsigned ln   = lane & 15u;    // 0..15
  const unsigned qw   = q0 + w * 16u;

  // ---- Q fragments, pre-scaled by 2*log2(e) ----
  f16x8 Qa0, Qa1;
  {
    const float* Qp = Q + (size_t)(bh * S_LEN + qw + ln) * DH + g * 8;
    const float s = 2.885390082f;  // 2 * log2(e)
    f32x4 a = *(const f32x4*)(Qp)      * s;
    f32x4 b = *(const f32x4*)(Qp + 4)  * s;
    f32x4 c = *(const f32x4*)(Qp + 32) * s;
    f32x4 d = *(const f32x4*)(Qp + 36) * s;
    Qa0 = pk8(a, b);
    Qa1 = pk8(c, d);
  }

  float mrun[4], lpart[4];
  f32x4 accO[4];
#pragma unroll
  for (int r = 0; r < 4; ++r) { mrun[r] = -1e30f; lpart[r] = 0.0f; }
#pragma unroll
  for (int n = 0; n < 4; ++n) accO[n] = (f32x4){0.f, 0.f, 0.f, 0.f};

  const unsigned kk  = tid >> 2;          // 0..63 K staging row
  const unsigned dgf = (tid & 3u) * 16u;  // 16 floats per thread

  // ---- prologue: prefetch K tile 0 into registers ----
  f32x4 kr0, kr1, kr2, kr3;
  {
    const float* Kp = K + (size_t)(bh * S_LEN + kk) * DH + dgf;
    kr0 = *(const f32x4*)(Kp);  kr1 = *(const f32x4*)(Kp + 4);
    kr2 = *(const f32x4*)(Kp + 8); kr3 = *(const f32x4*)(Kp + 12);
  }

  const float* Vg_base = V + (size_t)bh * S_LEN * DH + g * 8 * DH + ln;

  for (int t = 0; t < NIT; ++t) {
    __syncthreads();   // previous K tile fully consumed
    // ---- write staged K regs (tile t) to LDS ----
    *(f16x8*)&Kl[kk][dgf]     = pk8(kr0, kr1);
    *(f16x8*)&Kl[kk][dgf + 8] = pk8(kr2, kr3);
    __syncthreads();

    // ---- issue K prefetch for tile t+1 (oldest in VMEM queue) ----
    {
      int tn = (t + 1 < NIT) ? t + 1 : NIT - 1;   // clamp: last iter re-reads
      const float* Kp = K + (size_t)(bh * S_LEN + tn * KVB + kk) * DH + dgf;
      kr0 = *(const f32x4*)(Kp);  kr1 = *(const f32x4*)(Kp + 4);
      kr2 = *(const f32x4*)(Kp + 8); kr3 = *(const f32x4*)(Kp + 12);
    }

    // ---- V B-fragments direct from global (64 dword loads, imm offsets),
    //      converted to fp16 immediately to cap VGPR pressure ----
    f16x8 vb0[4], vb1[4];
    {
      const float* Vg = Vg_base + (size_t)t * KVB * DH;
#pragma unroll
      for (int nd = 0; nd < 4; ++nd) {
        f32x4 a, b, c, d;
#pragma unroll
        for (int j = 0; j < 4; ++j) {
          a[j] = Vg[(j)      * DH + nd * 16];
          b[j] = Vg[(4 + j)  * DH + nd * 16];
          c[j] = Vg[(32 + j) * DH + nd * 16];
          d[j] = Vg[(36 + j) * DH + nd * 16];
        }
        vb0[nd] = pk8(a, b);   // k = g*8 + 0..7
        vb1[nd] = pk8(c, d);   // k = 32 + g*8 + 0..7
      }
    }

    // ---- S2 = (2*log2e*Q) K^T : 16 q-rows x 64 k-cols ----
    f32x4 sc[4];
#pragma unroll
    for (int nt = 0; nt < 4; ++nt) {
      f16x8 kb0 = *(const f16x8*)&Kl[nt * 16 + ln][g * 8];
      f16x8 kb1 = *(const f16x8*)&Kl[nt * 16 + ln][32 + g * 8];
      f32x4 a = (f32x4){0.f, 0.f, 0.f, 0.f};
      a = __builtin_amdgcn_mfma_f32_16x16x32_f16(Qa0, kb0, a, 0, 0, 0);
      a = __builtin_amdgcn_mfma_f32_16x16x32_f16(Qa1, kb1, a, 0, 0, 0);
      sc[nt] = a;
    }

    // ---- dropout (threefry) + per-lane partial row max ----
    float sm[4][4];
    float pmx[4];
#pragma unroll
    for (int r = 0; r < 4; ++r) pmx[r] = -1e30f;
#pragma unroll
    for (int nt = 0; nt < 4; ++nt) {
#pragma unroll
      for (int r = 0; r < 4; ++r) {
        unsigned q  = qw + g * 4 + r;
        unsigned kg = (unsigned)t * KVB + nt * 16 + ln;
        unsigned e  = (bh << 20) + (q << 10) + kg;
        float v = keep_bit(e) ? sc[nt][r] : 0.0f;   // dropped -> 0 (log2 dom.)
        sm[nt][r] = v;
        pmx[r] = fmaxf(pmx[r], v);
      }
    }

    // ---- T13: ballot-gated max update + rescale (rare-ish path) ----
    bool need = (pmx[0] > mrun[0] + THR) | (pmx[1] > mrun[1] + THR) |
                (pmx[2] > mrun[2] + THR) | (pmx[3] > mrun[3] + THR);
    if (__any(need)) {
#pragma unroll
      for (int r = 0; r < 4; ++r) {
        float mx = pmx[r];
#pragma unroll
        for (int off = 1; off < 16; off <<= 1) mx = fmaxf(mx, __shfl_xor(mx, off));
        float mn  = fmaxf(mrun[r], mx);
        float scl = exp2f(mrun[r] - mn);
        mrun[r] = mn;
        lpart[r] *= scl;
#pragma unroll
        for (int n = 0; n < 4; ++n) accO[n][r] *= scl;
      }
    }

    // ---- P = 2^(S - m); per-lane partial sum only ----
    float ps[4][4];
#pragma unroll
    for (int nt = 0; nt < 4; ++nt) {
#pragma unroll
      for (int r = 0; r < 4; ++r) {
        float p = exp2f(sm[nt][r] - mrun[r]);
        ps[nt][r] = p;
        lpart[r] += p;
      }
    }

    // ---- P -> wave-private LDS (re-layout for PV A-frag) ----
#pragma unroll
    for (int nt = 0; nt < 4; ++nt)
#pragma unroll
      for (int r = 0; r < 4; ++r)
        Pl[w][g * 4 + r][nt * 16 + ln] = (_Float16)ps[nt][r];

    // ---- O += P V (V frags already in registers) ----
    f16x8 Pa0 = *(const f16x8*)&Pl[w][ln][g * 8];
    f16x8 Pa1 = *(const f16x8*)&Pl[w][ln][32 + g * 8];
#pragma unroll
    for (int nd = 0; nd < 4; ++nd) {
      accO[nd] = __builtin_amdgcn_mfma_f32_16x16x32_f16(Pa0, vb0[nd], accO[nd], 0, 0, 0);
      accO[nd] = __builtin_amdgcn_mfma_f32_16x16x32_f16(Pa1, vb1[nd], accO[nd], 0, 0, 0);
    }
  }

  // ---- epilogue: reduce l across the 16 k-lanes once, then O / l ----
  float lf[4];
#pragma unroll
  for (int r = 0; r < 4; ++r) {
    float l = lpart[r];
#pragma unroll
    for (int off = 1; off < 16; off <<= 1) l += __shfl_xor(l, off);
    lf[r] = l;
  }
#pragma unroll
  for (int nd = 0; nd < 4; ++nd) {
#pragma unroll
    for (int r = 0; r < 4; ++r) {
      unsigned q = qw + g * 4 + r;
      out[(size_t)(bh * S_LEN + q) * DH + nd * 16 + ln] = accO[nd][r] / lf[r];
    }
  }
}

extern "C" void kernel_launch(void* const* d_in, const int* in_sizes, int n_in,
                              void* d_out, int out_size, void* d_ws, size_t ws_size,
                              hipStream_t stream) {
  const float* Q = (const float*)d_in[0];
  const float* K = (const float*)d_in[1];
  const float* V = (const float*)d_in[2];
  float* out = (float*)d_out;
  dim3 grid(64 * 16);   // (b*16+h) * 16 q-tiles
  dim3 block(256);
  hipLaunchKernelGGL(attn_dropout_kernel, grid, block, 0, stream, Q, K, V, out);
}